// Round 3
// baseline (173.873 us; speedup 1.0000x reference)
//
#include <hip/hip_runtime.h>
#include <stdint.h>

// Problem constants (from reference)
#define BATCH 8192
#define FEAT 768
#define NCVX 32768            // BATCH * MULTIPLE_CONVEX
#define NOUT (BATCH + NCVX)   // 40960
#define UNSEEN 150

// Native 4-wide float vector (nontemporal builtin rejects HIP's float4 class).
typedef float f32x4 __attribute__((ext_vector_type(4)));

#define ROW_CHUNKS (FEAT / 4)                          // 192 float4 per row
constexpr int COPY_CHUNKS = BATCH * ROW_CHUNKS;        // 1572864
constexpr int LAB_CHUNKS  = NOUT / 4;                  // 10240

// Persistent grid: 2048 blocks x 256 = 8 blocks/CU (32 waves/CU, occupancy max).
constexpr int BLOCKS   = 2048;
constexpr int NTHREADS = BLOCKS * 256;                 // 524288
constexpr int NWAVES   = NTHREADS / 64;                // 8192 -> 4 convex rows/wave

// R2 theory: kernel is latency/overhead-bound (harness fill streams 480 MB at
// 6.6 TB/s in 76 us; our kernel moves ~350 MB worst-case in ~95 us).
// Fix: one WAVE owns one convex row -> s/idx loads are 3 wave-uniform loads
// per 6 KB of row traffic (was 3 loads per 16 B chunk), and each lane issues
// 6 independent gather loads (MLP), nt stores throughout.
__global__ __launch_bounds__(256) void ConvexSampler_39006892982339_kernel(
    const float* __restrict__ z,       // f32 [BATCH, FEAT]
    const int*   __restrict__ labels,  // i32 [BATCH]
    const int*   __restrict__ idx_i,   // i32 [NCVX]
    const int*   __restrict__ idx_j,   // i32 [NCVX]
    const float* __restrict__ s,       // f32 [NCVX]
    float*       __restrict__ out)     // f32 [NOUT*FEAT + NOUT]
{
    const int tid  = blockIdx.x * 256 + threadIdx.x;
    const int lane = threadIdx.x & 63;
    const int wid  = tid >> 6;

    const f32x4* z4   = (const f32x4*)z;
    f32x4*       out4 = (f32x4*)out;

    // Phase 1: straight copy z -> out[0 : BATCH*FEAT]. Grid-stride, fully
    // coalesced; caching loads warm L3 with z for the gather phase.
    #pragma unroll
    for (int it = 0; it < COPY_CHUNKS / NTHREADS; ++it) {   // exactly 3 iters
        int c = tid + it * NTHREADS;
        __builtin_nontemporal_store(z4[c], &out4[c]);
    }

    // Phase 2: convex rows, one row per wave per iteration (4 rows/wave).
    for (int row = wid; row < NCVX; row += NWAVES) {
        float sw  = s[row];
        float sw1 = 1.0f - sw;
        const f32x4* ap = z4 + (size_t)idx_i[row] * ROW_CHUNKS;
        const f32x4* bp = z4 + (size_t)idx_j[row] * ROW_CHUNKS;
        f32x4*       op = out4 + COPY_CHUNKS + (size_t)row * ROW_CHUNKS;

        // 192 chunks / 64 lanes = 3 chunks per lane; all 6 loads independent.
        f32x4 a0 = ap[lane];
        f32x4 a1 = ap[lane + 64];
        f32x4 a2 = ap[lane + 128];
        f32x4 b0 = bp[lane];
        f32x4 b1 = bp[lane + 64];
        f32x4 b2 = bp[lane + 128];
        __builtin_nontemporal_store(sw * a0 + sw1 * b0, &op[lane]);
        __builtin_nontemporal_store(sw * a1 + sw1 * b1, &op[lane + 64]);
        __builtin_nontemporal_store(sw * a2 + sw1 * b2, &op[lane + 128]);
    }

    // Phase 3: labels as f32 at out[NOUT*FEAT ..]. 10240 chunks < NTHREADS.
    if (tid < LAB_CHUNKS) {
        int base = tid * 4;
        f32x4 r;
        r.x = (float)(base + 0 < BATCH ? labels[base + 0] : UNSEEN);
        r.y = (float)(base + 1 < BATCH ? labels[base + 1] : UNSEEN);
        r.z = (float)(base + 2 < BATCH ? labels[base + 2] : UNSEEN);
        r.w = (float)(base + 3 < BATCH ? labels[base + 3] : UNSEEN);
        __builtin_nontemporal_store(r, &((f32x4*)(out + (size_t)NOUT * FEAT))[tid]);
    }
}

extern "C" void kernel_launch(void* const* d_in, const int* in_sizes, int n_in,
                              void* d_out, int out_size, void* d_ws, size_t ws_size,
                              hipStream_t stream) {
    const float* z      = (const float*)d_in[0];
    const int*   labels = (const int*)d_in[1];
    const int*   idx_i  = (const int*)d_in[2];
    const int*   idx_j  = (const int*)d_in[3];
    const float* s      = (const float*)d_in[4];
    float*       out    = (float*)d_out;

    ConvexSampler_39006892982339_kernel<<<BLOCKS, 256, 0, stream>>>(
        z, labels, idx_i, idx_j, s, out);
}